// Round 16
// baseline (254.076 us; speedup 1.0000x reference)
//
#include <hip/hip_runtime.h>

// CircuitModel: sequential Oja/Hebbian plasticity scan.
//   y_t = sigmoid(w_t.x_t); w_{t+1} = b_t*w_t + a_t*x_t,
//   a_t = lr*th0*y_t, b_t = 1 + lr*th1*y_t^2; out[t,p] = y_t at observed rows.
//
// R1: __shfl_xor = LDS swizzle ~120cy/step -> DPP reduce.
// R2: readlane is int(int,int) — must bitcast.
// R3-R6: compiler collapsed every register prefetch pipeline.
// R7-R9: LDS pipelines stuck ~390us (store drain + 4x LDS pipe re-read).
// R10: asm loads + tied vmcnt(1): 300us; compute hoisted above prefetch.
// R11: PIN pinned compute between load-issue and wait: 234us scan.
// R12: 2 waves/SIMD — per-ROW cost identical (1795cy), wall 2x: per-row
//     cost is VALU-slot bound (~4cy/inst eff.), invariant to co-scheduling.
// R13: v_pk_fma_f32 is half issue-rate — packed FP32 is not a lever.
// R14 BROKEN: hand-chained v_add_f32_dpp hits the VALU->DPP RAW hazard.
// R15: builtin DPP + batched w-update + log2e weights: 191.6us scan.
// R16: interleaved prefix-scaled w-update: acc += (a_i*rinv)*x_i inside the
//     step loop (fills sigmoid-chain bubbles; independent of z-chain);
//     rinv via rb=2-b (1st-order rcp, err e^2 ~ 4e-7); tail = 8 muls
//     (w' = prod*acc since c_i = B*u_i). Kills the 88-inst dense tail.

constexpr int N_IN    = 512;
constexpr int T       = 2048;
constexpr int N_OBS   = 256;
constexpr int D       = 8;            // linearization block size
constexpr int NBLK    = T / D;        // 256
constexpr int BANDPAD = 64;           // packed-band floats per block (28 used)
constexpr float LOG2E = 1.44269504088896f;

typedef float f4 __attribute__((ext_vector_type(4)));

// Packed band layout for block b (t0=8b): entry k = x_{t0+i}.x_{t0+i+j},
// k = BOFF[i] + (j-1), i=0..6, j=1..7-i (28 entries).
__device__ constexpr int BOFF[8] = {0, 7, 13, 18, 22, 25, 27, 28};

// DPP add-reduce step via builtin (old=0 additive identity; compiler handles
// the VALU->DPP hazard slots — R14 lesson).
#define DPP_ADD(v, ctrl, rmask)                                                \
    v += __int_as_float(__builtin_amdgcn_update_dpp(                           \
        0, __float_as_int(v), (ctrl), (rmask), 0xf, false))

__device__ __forceinline__ float wave64_sum_bcast(float v) {
    DPP_ADD(v, 0x111, 0xf); // row_shr:1
    DPP_ADD(v, 0x112, 0xf); // row_shr:2
    DPP_ADD(v, 0x114, 0xf); // row_shr:4
    DPP_ADD(v, 0x118, 0xf); // row_shr:8
    DPP_ADD(v, 0x142, 0xa); // row_bcast:15
    DPP_ADD(v, 0x143, 0xc); // row_bcast:31 -> lane63 = total
    return __int_as_float(__builtin_amdgcn_readlane(__float_as_int(v), 63));
}

// Serial-fma lane-partial dot: 8 insts, one chain (dots are mutually
// independent so chains overlap).
__device__ __forceinline__ float dot8s(const f4& w0, const f4& w1,
                                       const f4& x0, const f4& x1) {
    float p = w0.x * x0.x;
    p = fmaf(w0.y, x0.y, p);
    p = fmaf(w0.z, x0.z, p);
    p = fmaf(w0.w, x0.w, p);
    p = fmaf(w1.x, x1.x, p);
    p = fmaf(w1.y, x1.y, p);
    p = fmaf(w1.z, x1.z, p);
    p = fmaf(w1.w, x1.w, p);
    return p;
}

// ---- explicit-VMEM primitives ---------------------------------------------
#define GLOADX(dst, addr, offstr)                                              \
    asm volatile("global_load_dwordx4 %0, %1, off offset:" offstr              \
                 : "=v"(dst) : "v"(addr))

// Stage one block's 8 x-rows: exactly 16 vmem load issues, program-ordered.
__device__ __forceinline__ void stage16(f4 (&xb)[16], const char* xa) {
    const char* a0 = xa;
    const char* a1 = xa + 4096;
    const char* a2 = xa + 8192;
    const char* a3 = xa + 12288;
    GLOADX(xb[0],  a0, "0");    GLOADX(xb[1],  a0, "1024");
    GLOADX(xb[2],  a0, "2048"); GLOADX(xb[3],  a0, "3072");
    GLOADX(xb[4],  a1, "0");    GLOADX(xb[5],  a1, "1024");
    GLOADX(xb[6],  a1, "2048"); GLOADX(xb[7],  a1, "3072");
    GLOADX(xb[8],  a2, "0");    GLOADX(xb[9],  a2, "1024");
    GLOADX(xb[10], a2, "2048"); GLOADX(xb[11], a2, "3072");
    GLOADX(xb[12], a3, "0");    GLOADX(xb[13], a3, "1024");
    GLOADX(xb[14], a3, "2048"); GLOADX(xb[15], a3, "3072");
}

#define TIEBUF(ins, buf)                                                       \
    asm volatile(ins                                                           \
        : "+v"(buf[0]), "+v"(buf[1]), "+v"(buf[2]),  "+v"(buf[3]),             \
          "+v"(buf[4]), "+v"(buf[5]), "+v"(buf[6]),  "+v"(buf[7]),             \
          "+v"(buf[8]), "+v"(buf[9]), "+v"(buf[10]), "+v"(buf[11]),            \
          "+v"(buf[12]),"+v"(buf[13]),"+v"(buf[14]), "+v"(buf[15]))

// Pin: consumers of buf must schedule after this point (dataflow), and this
// point is after the preceding volatile loads (volatile order). Zero insts.
#define PIN(buf)      TIEBUF("", buf)
// Wait: drain all but the newest N outstanding vmem ops, tying buf's values.
#define WAIT1(buf)    TIEBUF("s_waitcnt vmcnt(1)", buf)
#define WAIT0(buf)    TIEBUF("s_waitcnt vmcnt(0)", buf)

// ---- Kernel 1: packed Gram band, one wave per 8-step block -----------------
__global__ __launch_bounds__(64) void gram_kernel(const float* __restrict__ X,
                                                  float* __restrict__ P) {
    const int b    = blockIdx.x;          // 0..NBLK-1
    const int lane = threadIdx.x;         // 0..63
    const int t0   = b * D;
    const f4* Xv = (const f4*)(X + (long)t0 * N_IN);
    f4 r[8][2];
    #pragma unroll
    for (int i = 0; i < 8; ++i) {
        r[i][0] = Xv[i * (N_IN / 4) + lane * 2 + 0];
        r[i][1] = Xv[i * (N_IN / 4) + lane * 2 + 1];
    }
    float s[28];
    #pragma unroll
    for (int i = 0; i < 7; ++i) {
        #pragma unroll
        for (int j = 1; j <= 7 - i; ++j) {
            s[BOFF[i] + j - 1] =
                wave64_sum_bcast(dot8s(r[i][0], r[i][1], r[i + j][0], r[i + j][1]));
        }
    }
    if (lane == 0) {
        #pragma unroll
        for (int k = 0; k < 28; ++k) P[b * BANDPAD + k] = s[k];
    }
}

// ---- process one block from a register buffer ------------------------------
// All z/q/w quantities are in log2e-scaled space (w~ = log2e*w); y itself is
// exact sigmoid via y = rcp(1 + 2^(-z~)).
__device__ __forceinline__ void process_block(
    const f4 (&xb)[16], const float (&bs)[28], int t0, int lane, int wave,
    f4& w0, f4& w1, float th0s, float th1, float* __restrict__ out)
{
    // Boundary: q~_d = w~_{t0} . x_{t0+d} (8 independent chains).
    float q[D];
    #pragma unroll
    for (int d = 0; d < D; ++d)
        q[d] = wave64_sum_bcast(dot8s(w0, w1, xb[2 * d], xb[2 * d + 1]));

    // Eight steps: sigmoid + q~ propagation + interleaved prefix-scaled
    // w-accumulation (acc-work is independent of the z-chain -> fills the
    // dependent-latency bubbles).  w' = prod * (w + sum_i u_i x_i),
    // u_i = a_i * rinv_i, rinv via rb = 2-b (1st-order reciprocal; b = 1+e,
    // |e| <~ 6e-4 -> error e^2 <~ 4e-7/step, negligible vs 0.02 threshold).
    f4 acc0 = w0, acc1 = w1;
    float prod = 1.0f;   // running prod of b_j  (suffix scale B at loop end)
    float rinv = 1.0f;   // ~ 1/prod
    float ys = 0.0f;
    float z = q[0];
    #pragma unroll
    for (int i = 0; i < D; ++i) {
        const float y =
            __builtin_amdgcn_rcpf(1.0f + __builtin_amdgcn_exp2f(-z));
        if (lane == i) ys = y;

        const float a = th0s * y;              // a~ = log2e * lr*th0 * y
        const float b = fmaf(th1 * y, y, 1.0f);

        #pragma unroll
        for (int d = i + 1; d < D; ++d)
            q[d] = fmaf(b, q[d], a * bs[BOFF[i] + (d - i) - 1]);
        if (i < D - 1) z = q[i + 1];

        prod *= b;
        rinv *= (2.0f - b);
        const float u = a * rinv;
        acc0.x = fmaf(u, xb[2 * i].x, acc0.x);
        acc0.y = fmaf(u, xb[2 * i].y, acc0.y);
        acc0.z = fmaf(u, xb[2 * i].z, acc0.z);
        acc0.w = fmaf(u, xb[2 * i].w, acc0.w);
        acc1.x = fmaf(u, xb[2 * i + 1].x, acc1.x);
        acc1.y = fmaf(u, xb[2 * i + 1].y, acc1.y);
        acc1.z = fmaf(u, xb[2 * i + 1].z, acc1.z);
        acc1.w = fmaf(u, xb[2 * i + 1].w, acc1.w);
    }

    // Tail: w' = prod * acc  (8 muls; the dense 88-inst tail is gone).
    w0.x = prod * acc0.x;  w0.y = prod * acc0.y;
    w0.z = prod * acc0.z;  w0.w = prod * acc0.w;
    w1.x = prod * acc1.x;  w1.y = prod * acc1.y;
    w1.z = prod * acc1.z;  w1.w = prod * acc1.w;

    // One batched store: lanes 0..7 write y_0..y_7 (exec-masked). Volatile:
    // stays before the following WAIT1, pinning the y dep-chain with it.
    float* oaddr = out + (size_t)(t0 + lane) * N_OBS + wave;
    asm volatile("s_mov_b64 vcc, exec\n\t"
                 "s_mov_b64 exec, 0xff\n\t"
                 "global_store_dword %0, %1, off\n\t"
                 "s_mov_b64 exec, vcc"
                 :: "v"(oaddr), "v"(ys) : "vcc");
}

__device__ __forceinline__ void load_band(float (&bs)[28], const float* pb) {
    #pragma unroll
    for (int k = 0; k < 28; ++k) bs[k] = pb[k];   // wave-uniform -> s_load
}

// ---- Kernel 2: the scan ----------------------------------------------------
__global__ __launch_bounds__(256, 1) void oja_scan_kernel(
    const float* __restrict__ X,     // [T, N_IN]
    const float* __restrict__ Winit, // [N_OUT, N_IN]
    const float* __restrict__ theta, // [2]
    const int*   __restrict__ obs,   // [N_OBS]
    const float* __restrict__ P,     // [NBLK, BANDPAD] packed band (d_ws)
    float*       __restrict__ out)   // [T, N_OBS]
{
    const int tid  = threadIdx.x;
    const int wid  = tid >> 6;            // 0..3 (1 wave per SIMD)
    const int lane = tid & 63;
    const int wave = blockIdx.x * 4 + wid; // observed-row index; always < 256

    const int row = obs[wave];
    const float lr   = 1.0f / (float)N_IN;
    const float th0s = theta[0] * lr * LOG2E;  // log2e-space a coefficient
    const float th1  = theta[1] * lr;

    // Ownership (R8): lane owns elements [4l,4l+4) and [256+4l,256+4l+4).
    // Weights held in log2e space: w~ = log2e * w.
    const f4* Wv = (const f4*)(Winit + (long)row * N_IN);
    f4 w0 = Wv[lane];
    f4 w1 = Wv[64 + lane];
    w0.x *= LOG2E; w0.y *= LOG2E; w0.z *= LOG2E; w0.w *= LOG2E;
    w1.x *= LOG2E; w1.y *= LOG2E; w1.z *= LOG2E; w1.w *= LOG2E;

    const char* xbase = (const char*)X + (size_t)lane * 16;

    f4 xA[16], xB[16];
    float bsA[28], bsB[28];

    // Prologue: block 0 into A, full drain.
    stage16(xA, xbase);
    load_band(bsA, P);
    WAIT0(xA);

    for (int blk = 0; blk < NBLK; blk += 2) {
        // Half 1: stage blk+1 into B; PIN(A) forces process(A)'s compute
        // after the loads; WAIT1 drains B's 16 loads (issued ~1 block ago),
        // leaving only the newest out-store in flight.
        const int b1 = (blk + 1 < NBLK) ? (blk + 1) : (NBLK - 1);
        stage16(xB, xbase + (size_t)b1 * 16384);
        load_band(bsB, P + (size_t)b1 * BANDPAD);
        PIN(xA);
        process_block(xA, bsA, blk * D, lane, wave, w0, w1, th0s, th1, out);
        WAIT1(xB);

        // Half 2: symmetric.
        const int b2 = (blk + 2 < NBLK) ? (blk + 2) : (NBLK - 1);
        stage16(xA, xbase + (size_t)b2 * 16384);
        load_band(bsA, P + (size_t)b2 * BANDPAD);
        PIN(xB);
        process_block(xB, bsB, (blk + 1) * D, lane, wave, w0, w1, th0s, th1, out);
        WAIT1(xA);
    }
}

extern "C" void kernel_launch(void* const* d_in, const int* in_sizes, int n_in,
                              void* d_out, int out_size, void* d_ws, size_t ws_size,
                              hipStream_t stream) {
    const float* X     = (const float*)d_in[0];
    const float* Winit = (const float*)d_in[1];
    const float* theta = (const float*)d_in[2];
    const int*   obs   = (const int*)d_in[3];
    float*       out   = (float*)d_out;
    float*       P     = (float*)d_ws;   // NBLK*BANDPAD floats = 64 KB

    // Gram band: one wave per block.
    gram_kernel<<<NBLK, 64, 0, stream>>>(X, P);

    // Scan: 64 WGs x 4 waves = 256 waves, one per SIMD on 64 CUs (R11 shape).
    oja_scan_kernel<<<64, 256, 0, stream>>>(X, Winit, theta, obs, P, out);
}

// Round 17
// 248.962 us; speedup vs baseline: 1.0205x; 1.0205x over previous
//
#include <hip/hip_runtime.h>

// CircuitModel: sequential Oja/Hebbian plasticity scan.
//   y_t = sigmoid(w_t.x_t); w_{t+1} = b_t*w_t + a_t*x_t,
//   a_t = lr*th0*y_t, b_t = 1 + lr*th1*y_t^2; out[t,p] = y_t at observed rows.
//
// R1: __shfl_xor = LDS swizzle ~120cy/step -> DPP reduce.
// R2: readlane is int(int,int) — must bitcast.
// R3-R6: compiler collapsed every register prefetch pipeline.
// R7-R9: LDS pipelines stuck ~390us (store drain + 4x LDS pipe re-read).
// R10: asm loads + tied vmcnt(1): 300us; compute hoisted above prefetch.
// R11: PIN pinned compute between load-issue and wait: 234us scan.
// R12: 2 waves/SIMD — per-ROW cost identical (1795cy): VALU-slot bound.
// R13: v_pk_fma_f32 is half issue-rate — packed FP32 is not a lever.
// R14 BROKEN: hand-chained v_add_f32_dpp hits the VALU->DPP RAW hazard.
// R15: builtin DPP + batched w-update + log2e weights: 191.6us scan (BEST).
// R16 NEUTRAL/REGRESSED (196.5us): in-loop prefix w-update added insts;
//     compiler was already bubble-filling R15's tail. VALU-slot floor
//     confirmed (~690 slots x 2cy + ~420cy chain residue = ~1810cy/block).
// R17: REVERT to R15 (best-known). Structural ceiling.

constexpr int N_IN    = 512;
constexpr int T       = 2048;
constexpr int N_OBS   = 256;
constexpr int D       = 8;            // linearization block size
constexpr int NBLK    = T / D;        // 256
constexpr int BANDPAD = 64;           // packed-band floats per block (28 used)
constexpr float LOG2E = 1.44269504088896f;

typedef float f4 __attribute__((ext_vector_type(4)));

// Packed band layout for block b (t0=8b): entry k = x_{t0+i}.x_{t0+i+j},
// k = BOFF[i] + (j-1), i=0..6, j=1..7-i (28 entries).
__device__ constexpr int BOFF[8] = {0, 7, 13, 18, 22, 25, 27, 28};

// DPP add-reduce step via builtin (old=0 additive identity; compiler handles
// the VALU->DPP hazard slots — R14 lesson).
#define DPP_ADD(v, ctrl, rmask)                                                \
    v += __int_as_float(__builtin_amdgcn_update_dpp(                           \
        0, __float_as_int(v), (ctrl), (rmask), 0xf, false))

__device__ __forceinline__ float wave64_sum_bcast(float v) {
    DPP_ADD(v, 0x111, 0xf); // row_shr:1
    DPP_ADD(v, 0x112, 0xf); // row_shr:2
    DPP_ADD(v, 0x114, 0xf); // row_shr:4
    DPP_ADD(v, 0x118, 0xf); // row_shr:8
    DPP_ADD(v, 0x142, 0xa); // row_bcast:15
    DPP_ADD(v, 0x143, 0xc); // row_bcast:31 -> lane63 = total
    return __int_as_float(__builtin_amdgcn_readlane(__float_as_int(v), 63));
}

// Serial-fma lane-partial dot: 8 insts, one chain (dots are mutually
// independent so chains overlap).
__device__ __forceinline__ float dot8s(const f4& w0, const f4& w1,
                                       const f4& x0, const f4& x1) {
    float p = w0.x * x0.x;
    p = fmaf(w0.y, x0.y, p);
    p = fmaf(w0.z, x0.z, p);
    p = fmaf(w0.w, x0.w, p);
    p = fmaf(w1.x, x1.x, p);
    p = fmaf(w1.y, x1.y, p);
    p = fmaf(w1.z, x1.z, p);
    p = fmaf(w1.w, x1.w, p);
    return p;
}

// ---- explicit-VMEM primitives ---------------------------------------------
#define GLOADX(dst, addr, offstr)                                              \
    asm volatile("global_load_dwordx4 %0, %1, off offset:" offstr              \
                 : "=v"(dst) : "v"(addr))

// Stage one block's 8 x-rows: exactly 16 vmem load issues, program-ordered.
__device__ __forceinline__ void stage16(f4 (&xb)[16], const char* xa) {
    const char* a0 = xa;
    const char* a1 = xa + 4096;
    const char* a2 = xa + 8192;
    const char* a3 = xa + 12288;
    GLOADX(xb[0],  a0, "0");    GLOADX(xb[1],  a0, "1024");
    GLOADX(xb[2],  a0, "2048"); GLOADX(xb[3],  a0, "3072");
    GLOADX(xb[4],  a1, "0");    GLOADX(xb[5],  a1, "1024");
    GLOADX(xb[6],  a1, "2048"); GLOADX(xb[7],  a1, "3072");
    GLOADX(xb[8],  a2, "0");    GLOADX(xb[9],  a2, "1024");
    GLOADX(xb[10], a2, "2048"); GLOADX(xb[11], a2, "3072");
    GLOADX(xb[12], a3, "0");    GLOADX(xb[13], a3, "1024");
    GLOADX(xb[14], a3, "2048"); GLOADX(xb[15], a3, "3072");
}

#define TIEBUF(ins, buf)                                                       \
    asm volatile(ins                                                           \
        : "+v"(buf[0]), "+v"(buf[1]), "+v"(buf[2]),  "+v"(buf[3]),             \
          "+v"(buf[4]), "+v"(buf[5]), "+v"(buf[6]),  "+v"(buf[7]),             \
          "+v"(buf[8]), "+v"(buf[9]), "+v"(buf[10]), "+v"(buf[11]),            \
          "+v"(buf[12]),"+v"(buf[13]),"+v"(buf[14]), "+v"(buf[15]))

// Pin: consumers of buf must schedule after this point (dataflow), and this
// point is after the preceding volatile loads (volatile order). Zero insts.
#define PIN(buf)      TIEBUF("", buf)
// Wait: drain all but the newest N outstanding vmem ops, tying buf's values.
#define WAIT1(buf)    TIEBUF("s_waitcnt vmcnt(1)", buf)
#define WAIT0(buf)    TIEBUF("s_waitcnt vmcnt(0)", buf)

// ---- Kernel 1: packed Gram band, one wave per 8-step block -----------------
__global__ __launch_bounds__(64) void gram_kernel(const float* __restrict__ X,
                                                  float* __restrict__ P) {
    const int b    = blockIdx.x;          // 0..NBLK-1
    const int lane = threadIdx.x;         // 0..63
    const int t0   = b * D;
    const f4* Xv = (const f4*)(X + (long)t0 * N_IN);
    f4 r[8][2];
    #pragma unroll
    for (int i = 0; i < 8; ++i) {
        r[i][0] = Xv[i * (N_IN / 4) + lane * 2 + 0];
        r[i][1] = Xv[i * (N_IN / 4) + lane * 2 + 1];
    }
    float s[28];
    #pragma unroll
    for (int i = 0; i < 7; ++i) {
        #pragma unroll
        for (int j = 1; j <= 7 - i; ++j) {
            s[BOFF[i] + j - 1] =
                wave64_sum_bcast(dot8s(r[i][0], r[i][1], r[i + j][0], r[i + j][1]));
        }
    }
    if (lane == 0) {
        #pragma unroll
        for (int k = 0; k < 28; ++k) P[b * BANDPAD + k] = s[k];
    }
}

// ---- process one block from a register buffer ------------------------------
// All z/q/w quantities are in log2e-scaled space (w~ = log2e*w); y itself is
// exact sigmoid, via y = rcp(1 + 2^(-z~)).
__device__ __forceinline__ void process_block(
    const f4 (&xb)[16], const float (&bs)[28], int t0, int lane, int wave,
    f4& w0, f4& w1, float th0s, float th1, float* __restrict__ out)
{
    // Boundary: q~_d = w~_{t0} . x_{t0+d} (8 independent chains).
    float q[D];
    #pragma unroll
    for (int d = 0; d < D; ++d)
        q[d] = wave64_sum_bcast(dot8s(w0, w1, xb[2 * d], xb[2 * d + 1]));

    // Eight steps: sigmoid + q~ propagation. w~-update deferred (batched).
    float av[D], bv[D];
    float ys = 0.0f;
    float z = q[0];
    #pragma unroll
    for (int i = 0; i < D; ++i) {
        const float y =
            __builtin_amdgcn_rcpf(1.0f + __builtin_amdgcn_exp2f(-z));
        if (lane == i) ys = y;

        const float a = th0s * y;              // a~ = log2e * lr*th0 * y
        const float b = fmaf(th1 * y, y, 1.0f);
        av[i] = a;
        bv[i] = b;

        #pragma unroll
        for (int d = i + 1; d < D; ++d)
            q[d] = fmaf(b, q[d], a * bs[BOFF[i] + (d - i) - 1]);
        if (i < D - 1) z = q[i + 1];
    }

    // Batched w~-update: w' = B*w + sum_i c_i x_i, c_i = a~_i * prod_{j>i} b_j.
    float c[D];
    float sfx = 1.0f;
    #pragma unroll
    for (int i = D - 1; i >= 0; --i) {
        c[i] = av[i] * sfx;
        sfx *= bv[i];
    }
    const float B = sfx;

    f4 acc0, acc1;
    acc0.x = c[0] * xb[0].x;  acc0.y = c[0] * xb[0].y;
    acc0.z = c[0] * xb[0].z;  acc0.w = c[0] * xb[0].w;
    acc1.x = c[0] * xb[1].x;  acc1.y = c[0] * xb[1].y;
    acc1.z = c[0] * xb[1].z;  acc1.w = c[0] * xb[1].w;
    #pragma unroll
    for (int i = 1; i < D; ++i) {
        acc0.x = fmaf(c[i], xb[2 * i].x, acc0.x);
        acc0.y = fmaf(c[i], xb[2 * i].y, acc0.y);
        acc0.z = fmaf(c[i], xb[2 * i].z, acc0.z);
        acc0.w = fmaf(c[i], xb[2 * i].w, acc0.w);
        acc1.x = fmaf(c[i], xb[2 * i + 1].x, acc1.x);
        acc1.y = fmaf(c[i], xb[2 * i + 1].y, acc1.y);
        acc1.z = fmaf(c[i], xb[2 * i + 1].z, acc1.z);
        acc1.w = fmaf(c[i], xb[2 * i + 1].w, acc1.w);
    }
    w0.x = fmaf(B, w0.x, acc0.x);
    w0.y = fmaf(B, w0.y, acc0.y);
    w0.z = fmaf(B, w0.z, acc0.z);
    w0.w = fmaf(B, w0.w, acc0.w);
    w1.x = fmaf(B, w1.x, acc1.x);
    w1.y = fmaf(B, w1.y, acc1.y);
    w1.z = fmaf(B, w1.z, acc1.z);
    w1.w = fmaf(B, w1.w, acc1.w);

    // One batched store: lanes 0..7 write y_0..y_7 (exec-masked). Volatile:
    // stays before the following WAIT1, pinning the y dep-chain with it.
    float* oaddr = out + (size_t)(t0 + lane) * N_OBS + wave;
    asm volatile("s_mov_b64 vcc, exec\n\t"
                 "s_mov_b64 exec, 0xff\n\t"
                 "global_store_dword %0, %1, off\n\t"
                 "s_mov_b64 exec, vcc"
                 :: "v"(oaddr), "v"(ys) : "vcc");
}

__device__ __forceinline__ void load_band(float (&bs)[28], const float* pb) {
    #pragma unroll
    for (int k = 0; k < 28; ++k) bs[k] = pb[k];   // wave-uniform -> s_load
}

// ---- Kernel 2: the scan ----------------------------------------------------
__global__ __launch_bounds__(256, 1) void oja_scan_kernel(
    const float* __restrict__ X,     // [T, N_IN]
    const float* __restrict__ Winit, // [N_OUT, N_IN]
    const float* __restrict__ theta, // [2]
    const int*   __restrict__ obs,   // [N_OBS]
    const float* __restrict__ P,     // [NBLK, BANDPAD] packed band (d_ws)
    float*       __restrict__ out)   // [T, N_OBS]
{
    const int tid  = threadIdx.x;
    const int wid  = tid >> 6;            // 0..3 (1 wave per SIMD)
    const int lane = tid & 63;
    const int wave = blockIdx.x * 4 + wid; // observed-row index; always < 256

    const int row = obs[wave];
    const float lr   = 1.0f / (float)N_IN;
    const float th0s = theta[0] * lr * LOG2E;  // log2e-space a coefficient
    const float th1  = theta[1] * lr;

    // Ownership (R8): lane owns elements [4l,4l+4) and [256+4l,256+4l+4).
    // Weights held in log2e space: w~ = log2e * w.
    const f4* Wv = (const f4*)(Winit + (long)row * N_IN);
    f4 w0 = Wv[lane];
    f4 w1 = Wv[64 + lane];
    w0.x *= LOG2E; w0.y *= LOG2E; w0.z *= LOG2E; w0.w *= LOG2E;
    w1.x *= LOG2E; w1.y *= LOG2E; w1.z *= LOG2E; w1.w *= LOG2E;

    const char* xbase = (const char*)X + (size_t)lane * 16;

    f4 xA[16], xB[16];
    float bsA[28], bsB[28];

    // Prologue: block 0 into A, full drain.
    stage16(xA, xbase);
    load_band(bsA, P);
    WAIT0(xA);

    for (int blk = 0; blk < NBLK; blk += 2) {
        // Half 1: stage blk+1 into B; PIN(A) forces process(A)'s compute
        // after the loads; WAIT1 drains B's 16 loads (issued ~1 block ago),
        // leaving only the newest out-store in flight.
        const int b1 = (blk + 1 < NBLK) ? (blk + 1) : (NBLK - 1);
        stage16(xB, xbase + (size_t)b1 * 16384);
        load_band(bsB, P + (size_t)b1 * BANDPAD);
        PIN(xA);
        process_block(xA, bsA, blk * D, lane, wave, w0, w1, th0s, th1, out);
        WAIT1(xB);

        // Half 2: symmetric.
        const int b2 = (blk + 2 < NBLK) ? (blk + 2) : (NBLK - 1);
        stage16(xA, xbase + (size_t)b2 * 16384);
        load_band(bsA, P + (size_t)b2 * BANDPAD);
        PIN(xB);
        process_block(xB, bsB, (blk + 1) * D, lane, wave, w0, w1, th0s, th1, out);
        WAIT1(xA);
    }
}

extern "C" void kernel_launch(void* const* d_in, const int* in_sizes, int n_in,
                              void* d_out, int out_size, void* d_ws, size_t ws_size,
                              hipStream_t stream) {
    const float* X     = (const float*)d_in[0];
    const float* Winit = (const float*)d_in[1];
    const float* theta = (const float*)d_in[2];
    const int*   obs   = (const int*)d_in[3];
    float*       out   = (float*)d_out;
    float*       P     = (float*)d_ws;   // NBLK*BANDPAD floats = 64 KB

    // Gram band: one wave per block.
    gram_kernel<<<NBLK, 64, 0, stream>>>(X, P);

    // Scan: 64 WGs x 4 waves = 256 waves, one per SIMD on 64 CUs (R11 shape).
    oja_scan_kernel<<<64, 256, 0, stream>>>(X, Winit, theta, obs, P, out);
}